// Round 1
// 129.117 us; speedup vs baseline: 1.0116x; 1.0116x over previous
//
#include <hip/hip_runtime.h>

static constexpr int Vn = 1024;   // codebook size
static constexpr int Dn = 256;    // code dim
static constexpr int NT = 65536;  // B * TOK

typedef float vfloat4 __attribute__((ext_vector_type(4)));  // native vec for stores

// ---------------------------------------------------------------------------
// Kernel 1: G = W * W^T (1024x1024, K=256), fp32.
// Round-5 rewrite: 64x64 tile per block (16x16 grid = 256 blocks, 1/CU),
// 4x4 outputs per thread => 16 fma per 8 broadcast-heavy ds_read_b32
// (was 4 fma per 4 reads). Staging is register-prefetched: chunk c+1's
// global loads issue under chunk c's 32-kk compute.
// EXACTNESS: per output element the fmaf chain is k=0..255 strictly
// ascending from 0.0f -- bit-identical G/norms to prior passing rounds.
// ---------------------------------------------------------------------------
__global__ __launch_bounds__(256) void gram_kernel(const float* __restrict__ W,
                                                   float* __restrict__ G,
                                                   float* __restrict__ norms) {
    __shared__ float As[64][33];   // [m][k-in-chunk], +1 pad: A-reads broadcast,
    __shared__ float Bs[64][33];   // B-reads 2-way (free, m136)
    const int tid = threadIdx.x;
    const int tx = tid & 15;       // 0..15 -> 4 consecutive cols
    const int ty = tid >> 4;       // 0..15 -> 4 consecutive rows
    const int bm = blockIdx.y * 64;
    const int bn = blockIdx.x * 64;
    const float4* Wv = (const float4*)W;   // [1024][64] float4, row = 64 f4

    // staging map: 64 rows x 8 float4 (32 k) per chunk = 512 f4; thread does
    // f4 #tid and #tid+256. 8 lanes/row -> 128 B contiguous per row.
    const int m0  = tid >> 3;      // 0..31 (s=0), +32 (s=1)
    const int kql = tid & 7;       // f4 within the 32-k chunk

    float4 pa[2], pb[2];
#pragma unroll
    for (int s = 0; s < 2; ++s) {  // prologue: chunk 0
        pa[s] = Wv[(bm + m0 + 32 * s) * 64 + kql];
        pb[s] = Wv[(bn + m0 + 32 * s) * 64 + kql];
    }

    float acc[4][4] = {};
    for (int c = 0; c < 8; ++c) {
        // regs -> LDS (writes land in distinct banks: m + 4*kq + comp mod 32)
#pragma unroll
        for (int s = 0; s < 2; ++s) {
            const int m = m0 + 32 * s;
            As[m][kql * 4 + 0] = pa[s].x;
            As[m][kql * 4 + 1] = pa[s].y;
            As[m][kql * 4 + 2] = pa[s].z;
            As[m][kql * 4 + 3] = pa[s].w;
            Bs[m][kql * 4 + 0] = pb[s].x;
            Bs[m][kql * 4 + 1] = pb[s].y;
            Bs[m][kql * 4 + 2] = pb[s].z;
            Bs[m][kql * 4 + 3] = pb[s].w;
        }
        __syncthreads();
        if (c < 7) {               // prefetch chunk c+1 under the compute below
            const int kq = (c + 1) * 8 + kql;
#pragma unroll
            for (int s = 0; s < 2; ++s) {
                pa[s] = Wv[(bm + m0 + 32 * s) * 64 + kq];
                pb[s] = Wv[(bn + m0 + 32 * s) * 64 + kq];
            }
        }
#pragma unroll
        for (int kk = 0; kk < 32; ++kk) {  // k ascending within chunk
            float a[4], b[4];
#pragma unroll
            for (int u = 0; u < 4; ++u) a[u] = As[ty * 4 + u][kk];
#pragma unroll
            for (int w = 0; w < 4; ++w) b[w] = Bs[tx * 4 + w][kk];
#pragma unroll
            for (int u = 0; u < 4; ++u)
#pragma unroll
                for (int w = 0; w < 4; ++w)
                    acc[u][w] = fmaf(a[u], b[w], acc[u][w]);
        }
        __syncthreads();
    }
    // epilogue: float4 stores (4 consecutive cols/thread -> 256 B per ty-row)
#pragma unroll
    for (int u = 0; u < 4; ++u) {
        const int row = bm + ty * 4 + u;
        vfloat4 o;
        o.x = acc[u][0]; o.y = acc[u][1]; o.z = acc[u][2]; o.w = acc[u][3];
        *(vfloat4*)(G + row * Vn + bn + tx * 4) = o;
        if (bm == bn && tx == ty) norms[row] = acc[u][u];  // fused diag
    }
}

// ---------------------------------------------------------------------------
// Kernel 2 (FUSED): per-token argmin + direct output write.
// UNCHANGED from the 130 µs round (bit-exact, passing). Block = 32 tokens,
// norms in registers, fmaf order identical -> identical argmin.
// ---------------------------------------------------------------------------
__global__ __launch_bounds__(256) void argmin_write_kernel(const int* __restrict__ seq,
                                                           const int* __restrict__ seq2,
                                                           const float* __restrict__ alpha,
                                                           const float* __restrict__ G,
                                                           const float* __restrict__ norms,
                                                           const float* __restrict__ W,
                                                           float* __restrict__ out) {
    __shared__ float T[32][129];   // [tok][d half], stride 129 -> <=2-way banks
    __shared__ int bestVs[32];
    const int tid = threadIdx.x;
    const int wave = tid >> 6;
    const int lane = tid & 63;
    const int t0 = blockIdx.x * 32;       // first token of block

    // norms for this lane's 16 v-slots: registers, reused by all 8 tokens
    float4 nn_r[4];
#pragma unroll
    for (int s = 0; s < 4; ++s) nn_r[s] = ((const float4*)norms)[s * 64 + lane];

    const float a = alpha[0];
    const float c0 = -2.0f * (1.0f - a);
    const float c1 = -2.0f * a;

    // ---- Phase 1: argmin for this wave's 8 tokens --------------------------
    for (int bb = 0; bb < 2; ++bb) {
        const int base_t = t0 + wave * 8 + bb * 4;   // global token of q=0
        const int base_l = wave * 8 + bb * 4;        // block-local
        int iv[4], jv[4];
#pragma unroll
        for (int q = 0; q < 4; ++q) { iv[q] = seq[base_t + q]; jv[q] = seq2[base_t + q]; }
#pragma unroll
        for (int pair = 0; pair < 2; ++pair) {
            const int qa = pair * 2, qb = pair * 2 + 1;
            const float4* GiA = (const float4*)(G + iv[qa] * Vn);
            const float4* GjA = (const float4*)(G + jv[qa] * Vn);
            const float4* GiB = (const float4*)(G + iv[qb] * Vn);
            const float4* GjB = (const float4*)(G + jv[qb] * Vn);
            float4 gia[4], gja[4], gib[4], gjb[4];
#pragma unroll
            for (int s = 0; s < 4; ++s) {
                const int e = s * 64 + lane;
                gia[s] = GiA[e];
                gja[s] = GjA[e];
                gib[s] = GiB[e];
                gjb[s] = GjB[e];
            }
            float bestA = __builtin_inff(), bestB = __builtin_inff();
            int vA = 0, vB = 0;
#pragma unroll
            for (int s = 0; s < 4; ++s) {
                const int e = s * 64 + lane;  // v = 4e..4e+3 ascending per lane
                const float4 nn = nn_r[s];
                const int v = e * 4;
                {
                    const float s0 = fmaf(c1, gja[s].x, fmaf(c0, gia[s].x, nn.x));
                    const float s1 = fmaf(c1, gja[s].y, fmaf(c0, gia[s].y, nn.y));
                    const float s2 = fmaf(c1, gja[s].z, fmaf(c0, gia[s].z, nn.z));
                    const float s3 = fmaf(c1, gja[s].w, fmaf(c0, gia[s].w, nn.w));
                    if (s0 < bestA) { bestA = s0; vA = v; }
                    if (s1 < bestA) { bestA = s1; vA = v + 1; }
                    if (s2 < bestA) { bestA = s2; vA = v + 2; }
                    if (s3 < bestA) { bestA = s3; vA = v + 3; }
                }
                {
                    const float s0 = fmaf(c1, gjb[s].x, fmaf(c0, gib[s].x, nn.x));
                    const float s1 = fmaf(c1, gjb[s].y, fmaf(c0, gib[s].y, nn.y));
                    const float s2 = fmaf(c1, gjb[s].z, fmaf(c0, gib[s].z, nn.z));
                    const float s3 = fmaf(c1, gjb[s].w, fmaf(c0, gib[s].w, nn.w));
                    if (s0 < bestB) { bestB = s0; vB = v; }
                    if (s1 < bestB) { bestB = s1; vB = v + 1; }
                    if (s2 < bestB) { bestB = s2; vB = v + 2; }
                    if (s3 < bestB) { bestB = s3; vB = v + 3; }
                }
            }
            // 64-lane reduce, lexicographic (score, v) = jnp.argmin first-min
#pragma unroll
            for (int off = 32; off >= 1; off >>= 1) {
                const float oa = __shfl_down(bestA, off, 64);
                const int   va = __shfl_down(vA, off, 64);
                if (oa < bestA || (oa == bestA && va < vA)) { bestA = oa; vA = va; }
                const float ob = __shfl_down(bestB, off, 64);
                const int   vb = __shfl_down(vB, off, 64);
                if (ob < bestB || (ob == bestB && vb < vB)) { bestB = ob; vB = vb; }
            }
            if (lane == 0) {
                bestVs[base_l + qa] = vA;
                bestVs[base_l + qb] = vB;
            }
        }
    }
    __syncthreads();

    // ---- Phase 2: two d-halves of 128; T[32][129] --------------------------
    const int b   = t0 >> 8;
    const int hw0 = t0 & 255;
    float* outb = out + b * 65536 + hw0;
    const int tok = tid >> 3;        // 0..31 (gather mapping)
    const int l8  = tid & 7;
    const int hw4  = (tid & 7) * 4;  // 0..28 (write mapping)
    const int drow = tid >> 3;       // 0..31
#pragma unroll
    for (int half = 0; half < 2; ++half) {
        // 2a: gather W rows -> T. 8 lanes/token, 128 B contiguous per token.
        const int v = bestVs[tok];
        const float4* Wr = (const float4*)(W + v * Dn + half * 128);
#pragma unroll
        for (int p = 0; p < 4; ++p) {
            const int d4 = p * 8 + l8;          // local float4 idx, 0..31
            const float4 w4 = Wr[d4];
            T[tok][d4 * 4 + 0] = w4.x;
            T[tok][d4 * 4 + 1] = w4.y;
            T[tok][d4 * 4 + 2] = w4.z;
            T[tok][d4 * 4 + 3] = w4.w;
        }
        __syncthreads();
        // 2b: transposed vfloat4 writes; each 8-lane group = one 128 B line.
#pragma unroll
        for (int dp = 0; dp < 128; dp += 32) {
            const int dl = dp + drow;           // local d, 0..127
            const int d = half * 128 + dl;
            vfloat4 o;
            o.x = T[hw4 + 0][dl];
            o.y = T[hw4 + 1][dl];
            o.z = T[hw4 + 2][dl];
            o.w = T[hw4 + 3][dl];
            __builtin_nontemporal_store(o, (vfloat4*)(outb + d * 256 + hw4));
        }
        __syncthreads();
    }
}

// ---------------------------------------------------------------------------
extern "C" void kernel_launch(void* const* d_in, const int* in_sizes, int n_in,
                              void* d_out, int out_size, void* d_ws, size_t ws_size,
                              hipStream_t stream) {
    const int*   seq   = (const int*)d_in[0];    // [256,256] int32
    const int*   seq2  = (const int*)d_in[1];    // [256,256] int32
    const float* alpha = (const float*)d_in[2];  // [1]
    const float* W     = (const float*)d_in[3];  // [1024,256] f32
    float* out = (float*)d_out;                  // [256,256,16,16] f32

    char* ws = (char*)d_ws;
    float* G     = (float*)(ws);             // 4 MB
    float* norms = (float*)(ws + 4194304);   // 4 KB

    gram_kernel<<<dim3(16, 16), 256, 0, stream>>>(W, G, norms);
    argmin_write_kernel<<<NT / 32, 256, 0, stream>>>(seq, seq2, alpha, G, norms, W, out);
}

// Round 2
// 124.344 us; speedup vs baseline: 1.0504x; 1.0384x over previous
//
#include <hip/hip_runtime.h>

static constexpr int Vn = 1024;   // codebook size
static constexpr int Dn = 256;    // code dim
static constexpr int NT = 65536;  // B * TOK

typedef float vfloat4 __attribute__((ext_vector_type(4)));  // native vec for stores

// ---------------------------------------------------------------------------
// Kernel 1: G = W * W^T (1024x1024, K=256), fp32. Round-6 fix:
// [k][m] LDS layout (stride 68 floats, 16B-aligned rows) so fragment reads are
// ds_read_b128:  a4 = As[kk][ty*4..+3]  (4 addrs/wave, 16 banks, bcast, clean)
//                b4 = Bs[kk][tx*4..+3]  (2-way alias = free)
// 2 vector reads + 16 FMA per kk (round-1 had 8 scalar reads with 8-way
// conflicts -- the post-mortem bug). Register double-buffered fragments.
// EXACTNESS: per output, fmaf chain k=0..255 ascending from 0.0f ->
// bit-identical G/norms to all prior passing rounds. G stored nontemporal
// (clean lines for argmin's cross-XCD reads; value bits unchanged).
// ---------------------------------------------------------------------------
__global__ __launch_bounds__(256) void gram_kernel(const float* __restrict__ W,
                                                   float* __restrict__ G,
                                                   float* __restrict__ norms) {
    __shared__ float As[32][68];   // [k-in-chunk][m], S=68: 16B-aligned, bank-shifted
    __shared__ float Bs[32][68];
    const int tid = threadIdx.x;
    const int tx = tid & 15;       // 0..15 -> 4 consecutive cols
    const int ty = tid >> 4;       // 0..15 -> 4 consecutive rows
    const int bm = blockIdx.y * 64;
    const int bn = blockIdx.x * 64;
    const float4* Wv = (const float4*)W;   // [1024][64] float4

    // staging map: 8 lanes/row -> 128 B contiguous global per row
    const int m0  = tid >> 3;      // 0..31 (s=0), +32 (s=1)
    const int kql = tid & 7;       // f4 within the 32-k chunk

    float4 pa[2], pb[2];
#pragma unroll
    for (int s = 0; s < 2; ++s) {  // prologue: chunk 0
        pa[s] = Wv[(bm + m0 + 32 * s) * 64 + kql];
        pb[s] = Wv[(bn + m0 + 32 * s) * 64 + kql];
    }

    float acc[4][4] = {};
    for (int c = 0; c < 8; ++c) {
        // regs -> LDS, transposed to [k][m]. 4-way b32 scatter (1.58x, minor).
#pragma unroll
        for (int s = 0; s < 2; ++s) {
            const int m = m0 + 32 * s;
            As[kql * 4 + 0][m] = pa[s].x;
            As[kql * 4 + 1][m] = pa[s].y;
            As[kql * 4 + 2][m] = pa[s].z;
            As[kql * 4 + 3][m] = pa[s].w;
            Bs[kql * 4 + 0][m] = pb[s].x;
            Bs[kql * 4 + 1][m] = pb[s].y;
            Bs[kql * 4 + 2][m] = pb[s].z;
            Bs[kql * 4 + 3][m] = pb[s].w;
        }
        __syncthreads();
        if (c < 7) {               // prefetch chunk c+1 under the compute below
            const int kq = (c + 1) * 8 + kql;
#pragma unroll
            for (int s = 0; s < 2; ++s) {
                pa[s] = Wv[(bm + m0 + 32 * s) * 64 + kq];
                pb[s] = Wv[(bn + m0 + 32 * s) * 64 + kq];
            }
        }
        // inner: 2 x ds_read_b128 + 16 FMA per kk, frag double-buffered
        const float* Ab = &As[0][ty * 4];
        const float* Bb = &Bs[0][tx * 4];
        float4 a_c = *(const float4*)Ab;
        float4 b_c = *(const float4*)Bb;
#pragma unroll
        for (int kk = 0; kk < 32; ++kk) {
            const int kn = (kk < 31) ? kk + 1 : kk;       // clamped prefetch
            const float4 a_n = *(const float4*)(Ab + kn * 68);
            const float4 b_n = *(const float4*)(Bb + kn * 68);
            const float a_s[4] = {a_c.x, a_c.y, a_c.z, a_c.w};
            const float b_s[4] = {b_c.x, b_c.y, b_c.z, b_c.w};
#pragma unroll
            for (int u = 0; u < 4; ++u)
#pragma unroll
                for (int w = 0; w < 4; ++w)
                    acc[u][w] = fmaf(a_s[u], b_s[w], acc[u][w]);  // k ascending
            a_c = a_n;
            b_c = b_n;
        }
        __syncthreads();
    }
    // epilogue: nontemporal float4 stores (clean lines for argmin's reads)
#pragma unroll
    for (int u = 0; u < 4; ++u) {
        const int row = bm + ty * 4 + u;
        vfloat4 o;
        o.x = acc[u][0]; o.y = acc[u][1]; o.z = acc[u][2]; o.w = acc[u][3];
        __builtin_nontemporal_store(o, (vfloat4*)(G + row * Vn + bn + tx * 4));
        if (bm == bn && tx == ty) norms[row] = acc[u][u];  // fused diag
    }
}

// ---------------------------------------------------------------------------
// Kernel 2 (FUSED): per-token argmin + direct output write.
// UNCHANGED (bit-exact, passing). Block = 32 tokens, norms in registers,
// fmaf order identical -> identical argmin.
// ---------------------------------------------------------------------------
__global__ __launch_bounds__(256) void argmin_write_kernel(const int* __restrict__ seq,
                                                           const int* __restrict__ seq2,
                                                           const float* __restrict__ alpha,
                                                           const float* __restrict__ G,
                                                           const float* __restrict__ norms,
                                                           const float* __restrict__ W,
                                                           float* __restrict__ out) {
    __shared__ float T[32][129];   // [tok][d half], stride 129 -> <=2-way banks
    __shared__ int bestVs[32];
    const int tid = threadIdx.x;
    const int wave = tid >> 6;
    const int lane = tid & 63;
    const int t0 = blockIdx.x * 32;       // first token of block

    // norms for this lane's 16 v-slots: registers, reused by all 8 tokens
    float4 nn_r[4];
#pragma unroll
    for (int s = 0; s < 4; ++s) nn_r[s] = ((const float4*)norms)[s * 64 + lane];

    const float a = alpha[0];
    const float c0 = -2.0f * (1.0f - a);
    const float c1 = -2.0f * a;

    // ---- Phase 1: argmin for this wave's 8 tokens --------------------------
    for (int bb = 0; bb < 2; ++bb) {
        const int base_t = t0 + wave * 8 + bb * 4;   // global token of q=0
        const int base_l = wave * 8 + bb * 4;        // block-local
        int iv[4], jv[4];
#pragma unroll
        for (int q = 0; q < 4; ++q) { iv[q] = seq[base_t + q]; jv[q] = seq2[base_t + q]; }
#pragma unroll
        for (int pair = 0; pair < 2; ++pair) {
            const int qa = pair * 2, qb = pair * 2 + 1;
            const float4* GiA = (const float4*)(G + iv[qa] * Vn);
            const float4* GjA = (const float4*)(G + jv[qa] * Vn);
            const float4* GiB = (const float4*)(G + iv[qb] * Vn);
            const float4* GjB = (const float4*)(G + jv[qb] * Vn);
            float4 gia[4], gja[4], gib[4], gjb[4];
#pragma unroll
            for (int s = 0; s < 4; ++s) {
                const int e = s * 64 + lane;
                gia[s] = GiA[e];
                gja[s] = GjA[e];
                gib[s] = GiB[e];
                gjb[s] = GjB[e];
            }
            float bestA = __builtin_inff(), bestB = __builtin_inff();
            int vA = 0, vB = 0;
#pragma unroll
            for (int s = 0; s < 4; ++s) {
                const int e = s * 64 + lane;  // v = 4e..4e+3 ascending per lane
                const float4 nn = nn_r[s];
                const int v = e * 4;
                {
                    const float s0 = fmaf(c1, gja[s].x, fmaf(c0, gia[s].x, nn.x));
                    const float s1 = fmaf(c1, gja[s].y, fmaf(c0, gia[s].y, nn.y));
                    const float s2 = fmaf(c1, gja[s].z, fmaf(c0, gia[s].z, nn.z));
                    const float s3 = fmaf(c1, gja[s].w, fmaf(c0, gia[s].w, nn.w));
                    if (s0 < bestA) { bestA = s0; vA = v; }
                    if (s1 < bestA) { bestA = s1; vA = v + 1; }
                    if (s2 < bestA) { bestA = s2; vA = v + 2; }
                    if (s3 < bestA) { bestA = s3; vA = v + 3; }
                }
                {
                    const float s0 = fmaf(c1, gjb[s].x, fmaf(c0, gib[s].x, nn.x));
                    const float s1 = fmaf(c1, gjb[s].y, fmaf(c0, gib[s].y, nn.y));
                    const float s2 = fmaf(c1, gjb[s].z, fmaf(c0, gib[s].z, nn.z));
                    const float s3 = fmaf(c1, gjb[s].w, fmaf(c0, gib[s].w, nn.w));
                    if (s0 < bestB) { bestB = s0; vB = v; }
                    if (s1 < bestB) { bestB = s1; vB = v + 1; }
                    if (s2 < bestB) { bestB = s2; vB = v + 2; }
                    if (s3 < bestB) { bestB = s3; vB = v + 3; }
                }
            }
            // 64-lane reduce, lexicographic (score, v) = jnp.argmin first-min
#pragma unroll
            for (int off = 32; off >= 1; off >>= 1) {
                const float oa = __shfl_down(bestA, off, 64);
                const int   va = __shfl_down(vA, off, 64);
                if (oa < bestA || (oa == bestA && va < vA)) { bestA = oa; vA = va; }
                const float ob = __shfl_down(bestB, off, 64);
                const int   vb = __shfl_down(vB, off, 64);
                if (ob < bestB || (ob == bestB && vb < vB)) { bestB = ob; vB = vb; }
            }
            if (lane == 0) {
                bestVs[base_l + qa] = vA;
                bestVs[base_l + qb] = vB;
            }
        }
    }
    __syncthreads();

    // ---- Phase 2: two d-halves of 128; T[32][129] --------------------------
    const int b   = t0 >> 8;
    const int hw0 = t0 & 255;
    float* outb = out + b * 65536 + hw0;
    const int tok = tid >> 3;        // 0..31 (gather mapping)
    const int l8  = tid & 7;
    const int hw4  = (tid & 7) * 4;  // 0..28 (write mapping)
    const int drow = tid >> 3;       // 0..31
#pragma unroll
    for (int half = 0; half < 2; ++half) {
        // 2a: gather W rows -> T. 8 lanes/token, 128 B contiguous per token.
        const int v = bestVs[tok];
        const float4* Wr = (const float4*)(W + v * Dn + half * 128);
#pragma unroll
        for (int p = 0; p < 4; ++p) {
            const int d4 = p * 8 + l8;          // local float4 idx, 0..31
            const float4 w4 = Wr[d4];
            T[tok][d4 * 4 + 0] = w4.x;
            T[tok][d4 * 4 + 1] = w4.y;
            T[tok][d4 * 4 + 2] = w4.z;
            T[tok][d4 * 4 + 3] = w4.w;
        }
        __syncthreads();
        // 2b: transposed vfloat4 writes; each 8-lane group = one 128 B line.
#pragma unroll
        for (int dp = 0; dp < 128; dp += 32) {
            const int dl = dp + drow;           // local d, 0..127
            const int d = half * 128 + dl;
            vfloat4 o;
            o.x = T[hw4 + 0][dl];
            o.y = T[hw4 + 1][dl];
            o.z = T[hw4 + 2][dl];
            o.w = T[hw4 + 3][dl];
            __builtin_nontemporal_store(o, (vfloat4*)(outb + d * 256 + hw4));
        }
        __syncthreads();
    }
}

// ---------------------------------------------------------------------------
extern "C" void kernel_launch(void* const* d_in, const int* in_sizes, int n_in,
                              void* d_out, int out_size, void* d_ws, size_t ws_size,
                              hipStream_t stream) {
    const int*   seq   = (const int*)d_in[0];    // [256,256] int32
    const int*   seq2  = (const int*)d_in[1];    // [256,256] int32
    const float* alpha = (const float*)d_in[2];  // [1]
    const float* W     = (const float*)d_in[3];  // [1024,256] f32
    float* out = (float*)d_out;                  // [256,256,16,16] f32

    char* ws = (char*)d_ws;
    float* G     = (float*)(ws);             // 4 MB
    float* norms = (float*)(ws + 4194304);   // 4 KB

    gram_kernel<<<dim3(16, 16), 256, 0, stream>>>(W, G, norms);
    argmin_write_kernel<<<NT / 32, 256, 0, stream>>>(seq, seq2, alpha, G, norms, W, out);
}